// Round 8
// baseline (929.716 us; speedup 1.0000x reference)
//
#include <hip/hip_runtime.h>
#include <cstdint>

#define ROTL32(v,n) (((v) << (n)) | ((v) >> (32 - (n))))

// ---- JAX threefry-2x32 (20 rounds, exact key-injection schedule) ----
__host__ __device__ __forceinline__ void tf2x32(uint32_t k0, uint32_t k1,
                                                uint32_t x0, uint32_t x1,
                                                uint32_t& o0, uint32_t& o1)
{
  uint32_t k2 = k0 ^ k1 ^ 0x1BD11BDAu;
  x0 += k0; x1 += k1;
#define TF_RND(r) { x0 += x1; x1 = ROTL32(x1, (r)); x1 ^= x0; }
  TF_RND(13) TF_RND(15) TF_RND(26) TF_RND(6)
  x0 += k1; x1 += k2 + 1u;
  TF_RND(17) TF_RND(29) TF_RND(16) TF_RND(24)
  x0 += k2; x1 += k0 + 2u;
  TF_RND(13) TF_RND(15) TF_RND(26) TF_RND(6)
  x0 += k0; x1 += k1 + 3u;
  TF_RND(17) TF_RND(29) TF_RND(16) TF_RND(24)
  x0 += k1; x1 += k2 + 4u;
  TF_RND(13) TF_RND(15) TF_RND(26) TF_RND(6)
  x0 += k2; x1 += k0 + 5u;
#undef TF_RND
  o0 = x0; o1 = x1;
}

typedef __attribute__((ext_vector_type(8))) _Float16 h16x8;
typedef __attribute__((ext_vector_type(4))) float fl32x4;

__device__ __forceinline__ float u2unit_g(uint32_t b) {
  uint32_t r = (b >> 9) | 0x3F800000u;
  float f; __builtin_memcpy(&f, &r, 4); return f - 1.0f;
}

#define GLD16(gp, lp) \
  __builtin_amdgcn_global_load_lds( \
      (__attribute__((address_space(1))) void*)(gp), \
      (__attribute__((address_space(3))) void*)(lp), 16, 0, 0)

#define VMW(n) asm volatile("s_waitcnt vmcnt(" #n ")" ::: "memory")
#define SBAR() asm volatile("s_barrier" ::: "memory")

// ---- x convert + pad (65536,784)f32 -> (65536,832)fp16 ----
__global__ __launch_bounds__(256) void cvt_x_g(const float* __restrict__ x,
                                               _Float16* __restrict__ xp)
{
  int idx = blockIdx.x * 256 + threadIdx.x;   // 65536*104 chunks of 8
  int row = idx / 104, c = idx - row * 104;
  h16x8 o = {0,0,0,0,0,0,0,0};
  if (c < 98) {
    const fl32x4* p = (const fl32x4*)&x[row * 784 + c * 8];
    fl32x4 a = p[0], b = p[1];
    o[0] = (_Float16)a[0]; o[1] = (_Float16)a[1]; o[2] = (_Float16)a[2]; o[3] = (_Float16)a[3];
    o[4] = (_Float16)b[0]; o[5] = (_Float16)b[1]; o[6] = (_Float16)b[2]; o[7] = (_Float16)b[3];
  }
  *(h16x8*)&xp[row * 832 + c * 8] = o;
}

// ---- weight transpose+convert (W1 padded to K=832) + bias concat b2..b7 ----
__global__ __launch_bounds__(256) void cvt_w_g(
    const float* __restrict__ W1, const float* __restrict__ W2, const float* __restrict__ W3,
    const float* __restrict__ W4, const float* __restrict__ W5, const float* __restrict__ W6,
    const float* __restrict__ W7,
    const float* __restrict__ B2, const float* __restrict__ B3, const float* __restrict__ B4,
    const float* __restrict__ B5, const float* __restrict__ B6, const float* __restrict__ B7,
    _Float16* __restrict__ WT1, _Float16* __restrict__ WT, float* __restrict__ ball)
{
  int b = blockIdx.x;
  if (b < 1666) {                              // 512*832 = 426496 elems
    int idx = b * 256 + threadIdx.x;           // n*832 + k
    int n = idx / 832, k = idx - n * 832;
    WT1[idx] = (k < 784) ? (_Float16)W1[k * 512 + n] : (_Float16)0.f;
  } else if (b < 7810) {                       // 6 layers of 512*512
    int l = (b - 1666) >> 10;
    int idx = ((b - 1666) & 1023) * 256 + threadIdx.x;
    int n = idx >> 9, k = idx & 511;
    const float* Wp = (l == 0) ? W2 : (l == 1) ? W3 : (l == 2) ? W4
                    : (l == 3) ? W5 : (l == 4) ? W6 : W7;
    WT[l * 262144 + idx] = (_Float16)Wp[k * 512 + n];
  } else {                                     // bias concat: 6*512 floats
    int idx = (b - 7810) * 256 + threadIdx.x;
    if (idx < 3072) {
      int l = idx >> 9;
      const float* Bp = (l == 0) ? B2 : (l == 1) ? B3 : (l == 2) ? B4
                      : (l == 3) ? B5 : (l == 4) ? B6 : B7;
      ball[idx] = Bp[idx & 511];
    }
  }
}

// ---- fused MLP: 128 rows/block persist in LDS across all 8 layers + softmax ----
// 512 thr / 8 waves; wave w owns rows [w*16, w*16+16) (wave-private h slice).
// W streamed from L2 in half-N (256xK32 = 16 KB) tiles, dbuf, counted vmcnt.
// LDS: h 128 KB (chunk-XOR swizzled) + 2 x 16 KB W = 160 KB exactly.
__global__ __launch_bounds__(512, 1) void mlp_fused_g(
    const _Float16* __restrict__ xp, const _Float16* __restrict__ WT1,
    const _Float16* __restrict__ WT, const float* __restrict__ b1,
    const float* __restrict__ ball, const float* __restrict__ W8,
    const float* __restrict__ b8, float* __restrict__ out,
    uint32_t d00, uint32_t d01, uint32_t d10, uint32_t d11,
    uint32_t d20, uint32_t d21)
{
  __shared__ __align__(16) _Float16 smem[81920];   // 163840 B = gfx950 max
  _Float16* hls = smem;            // [128][512] swizzled; bytes [0,16K) double as x dbuf in layer 1
  _Float16* Wb0 = smem + 65536;    // W half-buffer 0
  _Float16* Wb1 = smem + 73728;    // W half-buffer 1

  const int tid  = threadIdx.x;
  const int lane = tid & 63;
  const int wv   = tid >> 6;
  const int rml  = lane & 15;
  const int kq   = lane >> 4;
  const int rchunk = kq ^ (lane & 3) ^ ((lane >> 2) & 3);  // swizzled read chunk
  const int bm = blockIdx.x * 128;

// stage a 256-row x 32-k W half-tile (16 KB): linear LDS dest, inverse-swz source
#define WSTAGE(dstp, Wbase, K, half, kt) do {                                  \
    _Pragma("unroll") for (int g_ = 0; g_ < 2; ++g_) {                         \
      int id_ = g_*512 + tid;                                                  \
      int cs_ = (id_&3) ^ ((id_>>2)&3) ^ ((id_>>4)&3);                         \
      GLD16((Wbase) + (size_t)((half)*256 + (id_>>2))*(K) + (size_t)(kt)*32 + cs_*8, \
            (dstp) + (g_*512 + wv*64)*8); } } while(0)

// stage a 128-row x 32-k x tile (8 KB) into x dbuf corner of hls
#define XSTAGE(kt) do {                                                        \
    int cs_ = (tid&3) ^ ((tid>>2)&3) ^ ((tid>>4)&3);                           \
    GLD16(xp + (size_t)(bm + (tid>>2))*832 + (size_t)(kt)*32 + cs_*8,          \
          hls + (((kt)&1)*512 + wv*64)*8); } while(0)

// 16 MFMA for one n-half from a W half-buffer
#define MFMA16(basep, nbase, afv) do {                                         \
    _Pragma("unroll") for (int nn_ = 0; nn_ < 16; ++nn_) {                     \
      h16x8 bf_ = *(const h16x8*)((basep) + (nn_*16 + rml)*32 + rchunk*8);     \
      acc[(nbase) + nn_] = __builtin_amdgcn_mfma_f32_16x16x32_f16(             \
          afv, bf_, acc[(nbase)+nn_], 0,0,0); } } while(0)

// 4 threefry draws for this thread's 4 acc elements of n-frag = msub
#define TF4(msub, kh0v, kh1v, qhv) do {                                        \
    _Pragma("unroll") for (int i_ = 0; i_ < 4; ++i_) {                         \
      uint32_t j_ = (uint32_t)(bm + wv*16 + kq*4 + i_) * 512u                  \
                  + (uint32_t)((msub)*16 + rml);                               \
      uint32_t a_, c_; tf2x32((kh0v),(kh1v),0u,j_,a_,c_);                      \
      uint64_t bt_ = (u2unit_g(a_ ^ c_) < (qhv)) ? 1ull : 0ull;                \
      if ((msub) < 16) kb0 |= bt_ << (((msub)&15)*4 + i_);                     \
      else             kb1 |= bt_ << (((msub)&15)*4 + i_); } } while(0)

// bias + optional dropout + relu -> swizzled h write; re-zero acc
#define EPI(biasp, USEv, invqv, ka0, ka1) do {                                 \
    _Pragma("unroll") for (int n_ = 0; n_ < 32; ++n_) {                        \
      int col_ = n_*16 + rml;                                                  \
      float bv_ = (biasp)[col_];                                               \
      _Pragma("unroll") for (int r_ = 0; r_ < 4; ++r_) {                       \
        int row_ = wv*16 + kq*4 + r_;                                          \
        float v_ = acc[n_][r_] + bv_;                                          \
        if (USEv) {                                                            \
          uint64_t kb_ = (n_ < 16) ? (ka0) : (ka1);                            \
          v_ = ((kb_ >> ((n_&15)*4 + r_)) & 1ull) ? v_ * (invqv) : 0.0f; }     \
        v_ = fmaxf(v_, 0.0f);                                                  \
        hls[row_*512 + (((col_>>3) ^ (row_&7))*8) + (col_&7)] = (_Float16)v_;} \
      acc[n_] = (fl32x4){0.f,0.f,0.f,0.f}; } } while(0)

  fl32x4 acc[32];
#pragma unroll
  for (int i = 0; i < 32; ++i) acc[i] = (fl32x4){0.f,0.f,0.f,0.f};
  uint64_t kb0 = 0, kb1 = 0;

  // ================= layer 1: K=832, A = x (HBM), hosts masks for layer 2 =====
  XSTAGE(0); WSTAGE(Wb0, WT1, 832, 0, 0);
  VMW(0); SBAR();
#pragma unroll 1
  for (int kt = 0; kt < 26; ++kt) {
    WSTAGE(Wb1, WT1, 832, 1, kt);
    if (kt < 16) { TF4(2*kt, d00, d01, 0.8f); }
    VMW(2); SBAR();
    h16x8 af = *(const h16x8*)(hls + ((kt&1)*4096 + (wv*16 + rml)*32 + rchunk*8));
    MFMA16(Wb0, 0, af);
    SBAR();
    if (kt < 25) { XSTAGE(kt+1); WSTAGE(Wb0, WT1, 832, 0, kt+1); }
    if (kt < 16) { TF4(2*kt+1, d00, d01, 0.8f); }
    if (kt < 25) { VMW(3); } else { VMW(0); }
    SBAR();
    MFMA16(Wb1, 16, af);
    SBAR();
  }
  EPI(b1, 0, 1.0f, kb0, kb1);

  // ================= layers 2..7: K=512, A = h (LDS, wave-private) ============
#pragma unroll 1
  for (int layer = 2; layer <= 7; ++layer) {
    const _Float16* Wb = WT + (size_t)(layer-2)*262144;
    const float* bp = ball + (layer-2)*512;
    const int host = (layer == 3) || (layer == 5);
    const int use  = !(layer & 1);             // 2,4,6 apply dropout
    const uint32_t kh0 = (layer == 3) ? d10 : d20;
    const uint32_t kh1 = (layer == 3) ? d11 : d21;
    const float qh   = (layer == 3) ? 0.7f : 0.5f;
    const float invq = (layer == 2) ? 1.0f/0.8f : (layer == 4) ? 1.0f/0.7f : 2.0f;
    const uint64_t ukb0 = kb0, ukb1 = kb1;     // masks from previous hosting layer
    if (host) { kb0 = 0; kb1 = 0; }

    WSTAGE(Wb0, Wb, 512, 0, 0);
    VMW(0); SBAR();
#pragma unroll 1
    for (int kt = 0; kt < 16; ++kt) {
      WSTAGE(Wb1, Wb, 512, 1, kt);
      if (host) { TF4(2*kt, kh0, kh1, qh); }
      VMW(2); SBAR();
      h16x8 af = *(const h16x8*)(hls + ((wv*16 + rml)*512 + (((kt*4 + kq) ^ (rml & 7))*8)));
      MFMA16(Wb0, 0, af);
      SBAR();
      if (kt < 15) { WSTAGE(Wb0, Wb, 512, 0, kt+1); }
      if (host) { TF4(2*kt+1, kh0, kh1, qh); }
      if (kt < 15) { VMW(2); } else { VMW(0); }
      SBAR();
      MFMA16(Wb1, 16, af);
      SBAR();
    }
    EPI(bp, use, invq, ukb0, ukb1);
  }

  // ================= head: logits = h7@W8 + b8, softmax ======================
  __syncthreads();
  float* Wlf = (float*)Wb0;                    // 5120 f32 = 20 KB in W buffers
  for (int i = tid; i < 5120; i += 512) Wlf[i] = W8[i];
  __syncthreads();
  {
    int q  = lane & 3;                         // k-quarter
    int rw = lane >> 2;                        // row within wave (0..15)
    int row = wv*16 + rw;
    int hsh = row & 7;
    float s[10];
#pragma unroll
    for (int c = 0; c < 10; ++c) s[c] = 0.f;
#pragma unroll
    for (int i = 0; i < 16; ++i) {
      int c8 = q*16 + i;
      h16x8 hv = *(const h16x8*)(hls + row*512 + ((c8 ^ hsh)*8));
#pragma unroll
      for (int e = 0; e < 8; ++e) {
        float hf = (float)hv[e];
        int k = c8*8 + e;
#pragma unroll
        for (int c = 0; c < 10; ++c) s[c] += hf * Wlf[k*10 + c];
      }
    }
#pragma unroll
    for (int c = 0; c < 10; ++c) { s[c] += __shfl_xor(s[c], 1); s[c] += __shfl_xor(s[c], 2); }
    if (q == 0) {
      float mx = -3.0e38f;
#pragma unroll
      for (int c = 0; c < 10; ++c) { s[c] += b8[c]; mx = fmaxf(mx, s[c]); }
      float sum = 0.f, e10[10];
#pragma unroll
      for (int c = 0; c < 10; ++c) { e10[c] = expf(s[c] - mx); sum += e10[c]; }
      float is = 1.0f / sum;
#pragma unroll
      for (int c = 0; c < 10; ++c) out[(size_t)(bm + row)*10 + c] = e10[c] * is;
    }
  }
#undef WSTAGE
#undef XSTAGE
#undef MFMA16
#undef TF4
#undef EPI
}

extern "C" void kernel_launch(void* const* d_in, const int* in_sizes, int n_in,
                              void* d_out, int out_size, void* d_ws, size_t ws_size,
                              hipStream_t stream) {
  (void)in_sizes; (void)n_in; (void)out_size; (void)ws_size;
  const float* x = (const float*)d_in[0];
  const float* W[8]; const float* B[8];
  for (int i = 0; i < 8; ++i) { W[i] = (const float*)d_in[1 + 2*i]; B[i] = (const float*)d_in[2 + 2*i]; }

  char* w = (char*)d_ws;                       // ~113 MB total
  _Float16* xpad = (_Float16*)(w);             // 65536*832 fp16   = 109,051,904 B
  _Float16* WT1  = (_Float16*)(w + 109051904); // 512*832 fp16     =     851,968 B
  _Float16* WT   = (_Float16*)(w + 109903872); // 6 x 512*512 fp16 =   3,145,728 B
  float*    ball = (float*)   (w + 113049600); // 6*512 f32        =      12,288 B

  // jax.random.split(key(42), 3), threefry_partitionable (foldlike) path:
  // child i = BOTH output words of threefry(key=(0,42), counter=(0,i))
  uint32_t d00,d01,d10,d11,d20,d21;
  tf2x32(0u, 42u, 0u, 0u, d00, d01);           // dk[0]  (p=0.2, q=0.8)
  tf2x32(0u, 42u, 0u, 1u, d10, d11);           // dk[1]  (p=0.3, q=0.7)
  tf2x32(0u, 42u, 0u, 2u, d20, d21);           // dk[2]  (p=0.5, q=0.5)

  cvt_x_g<<<26624, 256, 0, stream>>>(x, xpad);
  cvt_w_g<<<7822, 256, 0, stream>>>(W[0],W[1],W[2],W[3],W[4],W[5],W[6],
                                    B[1],B[2],B[3],B[4],B[5],B[6], WT1, WT, ball);
  mlp_fused_g<<<512, 512, 0, stream>>>(xpad, WT1, WT, B[0], ball, W[7], B[7],
                                       (float*)d_out, d00,d01,d10,d11,d20,d21);
}

// Round 9
// 687.778 us; speedup vs baseline: 1.3518x; 1.3518x over previous
//
#include <hip/hip_runtime.h>
#include <cstdint>

#define ROTL32(v,n) (((v) << (n)) | ((v) >> (32 - (n))))

// ---- JAX threefry-2x32 (20 rounds, exact key-injection schedule) ----
__host__ __device__ __forceinline__ void tf2x32(uint32_t k0, uint32_t k1,
                                                uint32_t x0, uint32_t x1,
                                                uint32_t& o0, uint32_t& o1)
{
  uint32_t k2 = k0 ^ k1 ^ 0x1BD11BDAu;
  x0 += k0; x1 += k1;
#define TF_RND(r) { x0 += x1; x1 = ROTL32(x1, (r)); x1 ^= x0; }
  TF_RND(13) TF_RND(15) TF_RND(26) TF_RND(6)
  x0 += k1; x1 += k2 + 1u;
  TF_RND(17) TF_RND(29) TF_RND(16) TF_RND(24)
  x0 += k2; x1 += k0 + 2u;
  TF_RND(13) TF_RND(15) TF_RND(26) TF_RND(6)
  x0 += k0; x1 += k1 + 3u;
  TF_RND(17) TF_RND(29) TF_RND(16) TF_RND(24)
  x0 += k1; x1 += k2 + 4u;
  TF_RND(13) TF_RND(15) TF_RND(26) TF_RND(6)
  x0 += k2; x1 += k0 + 5u;
#undef TF_RND
  o0 = x0; o1 = x1;
}

typedef __attribute__((ext_vector_type(8))) _Float16 h16x8;
typedef __attribute__((ext_vector_type(4))) float fl32x4;

__device__ __forceinline__ float u2unit_f(uint32_t b) {
  uint32_t r = (b >> 9) | 0x3F800000u;
  float f; __builtin_memcpy(&f, &r, 4); return f - 1.0f;
}

// async global->LDS, 16B per lane; LDS dest = wave-uniform base + lane*16 (m104)
#define GLD16(gp, lp) \
  __builtin_amdgcn_global_load_lds( \
      (__attribute__((address_space(1))) void*)(gp), \
      (__attribute__((address_space(3))) void*)(lp), 16, 0, 0)

#define VMW(n) asm volatile("s_waitcnt vmcnt(" #n ")" ::: "memory")
#define SBAR() __builtin_amdgcn_s_barrier()

// ---- x convert + pad (65536,784)f32 -> (65536,832)fp16, + produce L0 masks ----
__global__ __launch_bounds__(256) void cvt_x_f(const float* __restrict__ x,
                                               _Float16* __restrict__ xp,
                                               unsigned long long* __restrict__ m0,
                                               uint32_t k0, uint32_t k1)
{
  int idx = blockIdx.x * 256 + threadIdx.x;   // 65536*104 chunks of 8
  int row = idx / 104, c = idx - row * 104;
  h16x8 o = {0,0,0,0,0,0,0,0};
  if (c < 98) {
    const fl32x4* p = (const fl32x4*)&x[row * 784 + c * 8];
    fl32x4 a = p[0], b = p[1];
    o[0] = (_Float16)a[0]; o[1] = (_Float16)a[1]; o[2] = (_Float16)a[2]; o[3] = (_Float16)a[3];
    o[4] = (_Float16)b[0]; o[5] = (_Float16)b[1]; o[6] = (_Float16)b[2]; o[7] = (_Float16)b[3];
  }
  *(h16x8*)&xp[row * 832 + c * 8] = o;

  // L0 dropout masks (p=0.2): 524288 words over 106496 waves -> 5 words/wave
  uint32_t lane = threadIdx.x & 63u;
  uint32_t gw = (uint32_t)blockIdx.x * 4u + ((uint32_t)threadIdx.x >> 6);
#pragma unroll
  for (int i = 0; i < 5; ++i) {
    uint32_t wix = gw * 5u + (uint32_t)i;
    if (wix < 524288u) {                      // wave-uniform guard
      uint32_t b1, b2;
      tf2x32(k0, k1, 0u, wix * 64u + lane, b1, b2);
      unsigned long long mw = __ballot(u2unit_f(b1 ^ b2) < 0.8f);
      if (lane == 0) m0[wix] = mw;
    }
  }
}

// ---- weight transpose+convert: W(K,N) f32 -> WT(N,K) fp16 (W1 padded to K=832) ----
__global__ __launch_bounds__(256) void cvt_w_f(
    const float* __restrict__ W1, const float* __restrict__ W2, const float* __restrict__ W3,
    const float* __restrict__ W4, const float* __restrict__ W5, const float* __restrict__ W6,
    const float* __restrict__ W7, _Float16* __restrict__ WT1, _Float16* __restrict__ WT)
{
  int b = blockIdx.x;
  if (b < 1666) {                              // 512*832 = 426496 elems
    int idx = b * 256 + threadIdx.x;           // n*832 + k
    int n = idx / 832, k = idx - n * 832;
    WT1[idx] = (k < 784) ? (_Float16)W1[k * 512 + n] : (_Float16)0.f;
  } else {                                     // 6 layers of 512*512
    int l = (b - 1666) >> 10;
    int idx = ((b - 1666) & 1023) * 256 + threadIdx.x;
    int n = idx >> 9, k = idx & 511;
    const float* Wp = (l == 0) ? W2 : (l == 1) ? W3 : (l == 2) ? W4
                    : (l == 3) ? W5 : (l == 4) ? W6 : W7;
    WT[l * 262144 + idx] = (_Float16)Wp[k * 512 + n];
  }
}

// ---- GEMM: 256x128 tile, BK=32, 512 thr / 8 waves, 3-buf LDS, vmcnt(3) pipeline ----
// Wave (wr=wv>>1, wc=wv&1): owns 64x64 output = 4x4 16x16 frags.
// LDS per buf: A 8192 elems (256x32) + B 4096 elems (128x32) = 24 KB; 3 bufs = 72 KB.
// Bank swizzle (128B pair-row lines): chunk (m,k16) stored at slot
//   ((m&1)<<2 | k16) ^ ((m>>1)&7); staging inverts it in the GLOBAL source.
template<bool DROP>
__global__ __launch_bounds__(512, 4) void gemm_t(
    const _Float16* __restrict__ A, const _Float16* __restrict__ BT,
    const float* __restrict__ bias, const unsigned long long* __restrict__ mask,
    float invq, _Float16* __restrict__ C, int K,
    unsigned long long* __restrict__ mout, uint32_t mbase,
    uint32_t mk0, uint32_t mk1, float mq)
{
  __shared__ __align__(16) _Float16 sm[36864];   // 73728 B
  const int tid  = threadIdx.x;
  const int lane = tid & 63;
  const int wv   = tid >> 6;
  const int wr   = wv >> 1, wc = wv & 1;
  const int rml  = lane & 15;
  const int kq   = lane >> 4;

  // XCD swizzle: 1024 blocks = 8 XCDs x 128; consecutive t share the A panel
  int bid = blockIdx.x;
  int t = (bid & 7) * 128 + (bid >> 3);
  int bm = (t >> 2) * 256;
  int bn = (t & 3) * 128;

  const _Float16* Ab = A + (size_t)bm * K;
  const _Float16* Bb = BT + (size_t)bn * K;

  // staging constants: thread handles chunks {tid, 512+tid} of A, {tid} of B
  const int sp   = tid >> 3;
  const int sin  = (tid & 7) ^ (sp & 7);           // inverse swizzle
  const int srow = 2 * sp + (sin >> 2);            // source m (0..127)
  const int sk16 = sin & 3;                        // source k-chunk

  // read constants: slot = ((rml&1)<<2 | kq) ^ (rml>>1)
  const int rslot = (((rml & 1) << 2) | kq) ^ (rml >> 1);
  const int abase = (wr * 32 + (rml >> 1)) * 64 + rslot * 8;
  const int bbase = 8192 + (wc * 32 + (rml >> 1)) * 64 + rslot * 8;

  fl32x4 acc[4][4];
#pragma unroll
  for (int i = 0; i < 4; ++i)
#pragma unroll
    for (int j = 0; j < 4; ++j)
      acc[i][j] = (fl32x4){0.f, 0.f, 0.f, 0.f};

  const int nst = K >> 5;

#define STAGE(bufe, kt) do {                                                   \
    GLD16(Ab + (size_t)srow * K + (kt) * 32 + sk16 * 8,                        \
          sm + (bufe) + wv * 512);                                             \
    GLD16(Ab + (size_t)(srow + 128) * K + (kt) * 32 + sk16 * 8,                \
          sm + (bufe) + 4096 + wv * 512);                                      \
    GLD16(Bb + (size_t)srow * K + (kt) * 32 + sk16 * 8,                        \
          sm + (bufe) + 8192 + wv * 512);                                      \
  } while (0)

  STAGE(0, 0);
  STAGE(12288, 1);
  VMW(3); SBAR();                                // buf0 ready; buf1 in flight

  int cur = 0;
#pragma unroll 1
  for (int kt = 0; kt < nst; ++kt) {
    int nxt2 = cur + 24576 >= 36864 ? cur - 12288 : cur + 24576;
    if (kt + 2 < nst) STAGE(nxt2, kt + 2);       // 3 loads, land 2 steps ahead
    // fused mask production for a later layer (2 words/step, 32/wave)
    if (mout != nullptr && kt < 16) {
      uint32_t gw = (uint32_t)bid * 8u + (uint32_t)wv;
#pragma unroll
      for (int i = 0; i < 2; ++i) {
        uint32_t wix = mbase + gw * 32u + (uint32_t)(kt * 2 + i);
        uint32_t b1, b2;
        tf2x32(mk0, mk1, 0u, wix * 64u + (uint32_t)lane, b1, b2);
        unsigned long long mw = __ballot(u2unit_f(b1 ^ b2) < mq);
        if (lane == 0) mout[wix] = mw;
      }
    }
    // compute current buffer
    h16x8 af[4];
#pragma unroll
    for (int mf = 0; mf < 4; ++mf)
      af[mf] = *(const h16x8*)&sm[cur + abase + mf * 512];
#pragma unroll
    for (int nf = 0; nf < 4; ++nf) {
      h16x8 bf = *(const h16x8*)&sm[cur + bbase + nf * 512];
#pragma unroll
      for (int mf = 0; mf < 4; ++mf)
        acc[mf][nf] = __builtin_amdgcn_mfma_f32_16x16x32_f16(af[mf], bf, acc[mf][nf], 0, 0, 0);
    }
    if (kt + 2 < nst) { VMW(3); } else { VMW(0); }   // next buf ready; 3 stay in flight
    SBAR();
    cur = (cur + 12288 >= 36864) ? 0 : cur + 12288;
  }
#undef STAGE

  // epilogue: bias + (dropout) + relu -> fp16. C/D map: col=lane&15, row=kq*4+r
  const int c0 = bn + wc * 64 + rml;
  const int r0 = bm + wr * 64 + kq * 4;
#pragma unroll
  for (int nf = 0; nf < 4; ++nf) {
    int col = c0 + nf * 16;
    float bv = bias[col];
#pragma unroll
    for (int mf = 0; mf < 4; ++mf) {
#pragma unroll
      for (int r = 0; r < 4; ++r) {
        int row = r0 + mf * 16 + r;
        float v = acc[mf][nf][r] + bv;
        if (DROP) {
          uint32_t j = (uint32_t)row * 512u + (uint32_t)col;
          unsigned long long mw = mask[j >> 6];
          v = ((mw >> (j & 63)) & 1ull) ? v * invq : 0.0f;
        }
        v = fmaxf(v, 0.0f);
        C[(size_t)row * 512 + col] = (_Float16)v;
      }
    }
  }
}

// ---- head: logits = h@W8 + b8 (512->10), softmax, fp32 out ----
__global__ __launch_bounds__(256) void head_f(
    const _Float16* __restrict__ H, const float* __restrict__ W8,
    const float* __restrict__ b8, float* __restrict__ out)
{
  __shared__ float Wl[5120];                   // 512x10 fp32
  for (int i = threadIdx.x; i < 5120; i += 256) Wl[i] = W8[i];
  __syncthreads();
  int lane = threadIdx.x & 63;
  int wv = threadIdx.x >> 6;
  int row = blockIdx.x * 4 + wv;               // one row per wave
  h16x8 h = *(const h16x8*)&H[(size_t)row * 512 + lane * 8];
  float acc[10];
#pragma unroll
  for (int n = 0; n < 10; ++n) acc[n] = 0.f;
#pragma unroll
  for (int j = 0; j < 8; ++j) {
    float hf = (float)h[j];
    const float* wrow = &Wl[(lane * 8 + j) * 10];
#pragma unroll
    for (int n = 0; n < 10; ++n) acc[n] += hf * wrow[n];
  }
#pragma unroll
  for (int off = 1; off < 64; off <<= 1) {
#pragma unroll
    for (int n = 0; n < 10; ++n) acc[n] += __shfl_xor(acc[n], off);
  }
  if (lane == 0) {
    float mx = -3.0e38f;
#pragma unroll
    for (int n = 0; n < 10; ++n) { acc[n] += b8[n]; mx = fmaxf(mx, acc[n]); }
    float s = 0.f, e[10];
#pragma unroll
    for (int n = 0; n < 10; ++n) { e[n] = expf(acc[n] - mx); s += e[n]; }
    float is = 1.0f / s;
#pragma unroll
    for (int n = 0; n < 10; ++n) out[(size_t)row * 10 + n] = e[n] * is;
  }
}

extern "C" void kernel_launch(void* const* d_in, const int* in_sizes, int n_in,
                              void* d_out, int out_size, void* d_ws, size_t ws_size,
                              hipStream_t stream) {
  (void)in_sizes; (void)n_in; (void)out_size; (void)ws_size;
  const float* x = (const float*)d_in[0];
  const float* W[8]; const float* B[8];
  for (int i = 0; i < 8; ++i) { W[i] = (const float*)d_in[1 + 2*i]; B[i] = (const float*)d_in[2 + 2*i]; }

  char* w = (char*)d_ws;                       // ~260 MB total
  _Float16* xpad = (_Float16*)(w);             // 65536*832 fp16   = 109,051,904 B
  _Float16* hA   = (_Float16*)(w + 109051904); // 65536*512 fp16   =  67,108,864 B
  _Float16* hB   = (_Float16*)(w + 176160768); // 65536*512 fp16   =  67,108,864 B
  _Float16* WT1  = (_Float16*)(w + 243269632); // 512*832 fp16     =     851,968 B
  _Float16* WT   = (_Float16*)(w + 244121600); // 6 x 512*512 fp16 =   3,145,728 B
  unsigned long long* masks = (unsigned long long*)(w + 247267328); // 3*4 MiB
  unsigned long long* mL0 = masks;
  unsigned long long* mL1 = masks + 524288;
  unsigned long long* mL2 = masks + 1048576;

  // jax.random.split(key(42), 3), threefry_partitionable (foldlike) path:
  // child i = BOTH output words of threefry(key=(0,42), counter=(0,i))
  uint32_t d00,d01,d10,d11,d20,d21;
  tf2x32(0u, 42u, 0u, 0u, d00, d01);           // dk[0]  (p=0.2, q=0.8)
  tf2x32(0u, 42u, 0u, 1u, d10, d11);           // dk[1]  (p=0.3, q=0.7)
  tf2x32(0u, 42u, 0u, 2u, d20, d21);           // dk[2]  (p=0.5, q=0.5)

  cvt_x_f<<<26624, 256, 0, stream>>>(x, xpad, mL0, d00, d01);
  cvt_w_f<<<7810, 256, 0, stream>>>(W[0],W[1],W[2],W[3],W[4],W[5],W[6], WT1, WT);

  dim3 g(1024), b(512);
  // masks: mL0 by cvt_x (used by g2); mL1 by g1+g2 (used by g4); mL2 by g3+g4 (used by g6)
  gemm_t<false><<<g, b, 0, stream>>>(xpad, WT1,           B[0], nullptr, 1.0f,      hA, 832,
                                     mL1, 0u,      d10, d11, 0.7f);
  gemm_t<true ><<<g, b, 0, stream>>>(hA,   WT + 0*262144, B[1], mL0,     1.0f/0.8f, hB, 512,
                                     mL1, 262144u, d10, d11, 0.7f);
  gemm_t<false><<<g, b, 0, stream>>>(hB,   WT + 1*262144, B[2], nullptr, 1.0f,      hA, 512,
                                     mL2, 0u,      d20, d21, 0.5f);
  gemm_t<true ><<<g, b, 0, stream>>>(hA,   WT + 2*262144, B[3], mL1,     1.0f/0.7f, hB, 512,
                                     mL2, 262144u, d20, d21, 0.5f);
  gemm_t<false><<<g, b, 0, stream>>>(hB,   WT + 3*262144, B[4], nullptr, 1.0f,      hA, 512,
                                     nullptr, 0u, 0u, 0u, 0.f);
  gemm_t<true ><<<g, b, 0, stream>>>(hA,   WT + 4*262144, B[5], mL2,     2.0f,      hB, 512,
                                     nullptr, 0u, 0u, 0u, 0.f);
  gemm_t<false><<<g, b, 0, stream>>>(hB,   WT + 5*262144, B[6], nullptr, 1.0f,      hA, 512,
                                     nullptr, 0u, 0u, 0u, 0.f);
  head_f<<<16384, 256, 0, stream>>>(hA, W[7], B[7], (float*)d_out);
}